// Round 10
// baseline (461.806 us; speedup 1.0000x reference)
//
#include <hip/hip_runtime.h>

static constexpr float SLOPE = 0.2f;
static constexpr float BN_EPS = 1e-5f;

static inline int cdiv(long long a, long long b) { return (int)((a + b - 1) / b); }

typedef __attribute__((ext_vector_type(8))) short short8;
typedef __attribute__((ext_vector_type(4))) float f32x4;

__device__ __forceinline__ unsigned short f2bf(float f) {
  unsigned u = __float_as_uint(f);
  u += 0x7fff + ((u >> 16) & 1);          // round-to-nearest-even
  return (unsigned short)(u >> 16);
}
__device__ __forceinline__ float bf2f(unsigned short h) {
  return __uint_as_float((unsigned)h << 16);
}

// ====================== CSR build: bucket-partitioned, LDS-staged ======================
static constexpr int EPB = 8192;        // edges per partition block
static constexpr int BCAP = 12288;      // LDS staging capacity in csr_bucket

// ---- merged: per-block bucket histogram + weight transpose + zeroing ----
// grid = NBLK + 144 + 48
__global__ void prep_hist(const int* __restrict__ ei, int* __restrict__ counts,
                          const float* __restrict__ W0, const float* __restrict__ W1,
                          const float* __restrict__ W2,
                          unsigned short* __restrict__ Wt0, unsigned short* __restrict__ Wt1,
                          unsigned short* __restrict__ Wt2,
                          float* __restrict__ SP0, float* __restrict__ SP1,
                          float* __restrict__ SP2,
                          int E, int NBLK, int NB) {
  const int tid = threadIdx.x;
  const int blk = blockIdx.x;
  if (blk < NBLK) {                      // histogram role
    __shared__ int cnt[256];
    cnt[tid] = 0;
    __syncthreads();
    const int i0 = blk * EPB;
    const int i1 = min(E, i0 + EPB);
    for (int i = i0 + tid; i < i1; i += 256) atomicAdd(&cnt[ei[E + i] >> 8], 1);
    __syncthreads();
    if (tid < NB) counts[tid * NBLK + blk] = cnt[tid];
    return;
  }
  const int b = blk - NBLK;
  if (b < 64) {                          // Wt0[j][k] = W0[k][j], 128x128
    int o = b * 256 + tid;
    int j = o >> 7, k = o & 127;
    Wt0[o] = f2bf(W0[k * 128 + j]);
  } else if (b < 128) {
    int o = (b - 64) * 256 + tid;
    int j = o >> 7, k = o & 127;
    Wt1[o] = f2bf(W1[k * 128 + j]);
  } else if (b < 144) {                  // Wt2[j][k] = W2[k][j], 32x128
    int o = (b - 128) * 256 + tid;
    int j = o >> 7, k = o & 127;
    Wt2[o] = f2bf(W2[k * 32 + j]);
  } else {                               // zero BN partial-slot arrays
    int idx = (b - 144) * 256 + tid;
    for (int i = idx; i < 36864; i += 48 * 256) {
      if (i < 16384) SP0[i] = 0.f;
      else if (i < 32768) SP1[i - 16384] = 0.f;
      else SP2[i - 32768] = 0.f;
    }
  }
}

// ---- chunked 2-pass exclusive scan, single block of 1024 ----
__global__ void csr_scan2(const int* __restrict__ counts, int* __restrict__ offsets, int m) {
  __shared__ int wtot[16];
  const int tid = threadIdx.x;
  const int lane = tid & 63, wv = tid >> 6;
  const int CH = (m + 1023) >> 10;
  const int lo = min(m, tid * CH);
  const int hi = min(m, lo + CH);
  int sum = 0;
  for (int i = lo; i < hi; ++i) sum += counts[i];
  int x = sum;
#pragma unroll
  for (int off = 1; off < 64; off <<= 1) {
    int y = __shfl_up(x, off);
    if (lane >= off) x += y;
  }
  if (lane == 63) wtot[wv] = x;
  __syncthreads();
  int add = 0;
  for (int w = 0; w < wv; ++w) add += wtot[w];
  int run = x - sum + add;
  for (int i = lo; i < hi; ++i) { offsets[i] = run; run += counts[i]; }
  if (hi == m) offsets[m] = run;
}

// ---- partition edges into bucket-major packed runs via LDS staging ----
__global__ __launch_bounds__(256) void csr_part(const int* __restrict__ ei,
                                                const int* __restrict__ offsets,
                                                unsigned* __restrict__ ebuf,
                                                int E, int NBLK, int NB) {
  __shared__ unsigned stage[EPB];        // 32 KB
  __shared__ int cnt[256], sstart[256], cur[256], goff[256];
  __shared__ int wtot[4];
  const int tid = threadIdx.x;
  const int blk = blockIdx.x;
  const int lane = tid & 63, wv = tid >> 6;
  cnt[tid] = 0;
  if (tid < NB) goff[tid] = offsets[tid * NBLK + blk];
  __syncthreads();
  const int i0 = blk * EPB;
  const int i1 = min(E, i0 + EPB);
  for (int i = i0 + tid; i < i1; i += 256) atomicAdd(&cnt[ei[E + i] >> 8], 1);
  __syncthreads();
  int v = cnt[tid];
  int x = v;
#pragma unroll
  for (int off = 1; off < 64; off <<= 1) {
    int y = __shfl_up(x, off);
    if (lane >= off) x += y;
  }
  if (lane == 63) wtot[wv] = x;
  __syncthreads();
  int add = 0;
  for (int w = 0; w < wv; ++w) add += wtot[w];
  int excl = x - v + add;
  sstart[tid] = excl;
  cur[tid] = excl;
  __syncthreads();
  for (int i = i0 + tid; i < i1; i += 256) {
    int s = ei[i], d = ei[E + i];
    int p = atomicAdd(&cur[d >> 8], 1);
    stage[p] = ((unsigned)s << 8) | (unsigned)(d & 255);
  }
  __syncthreads();
  for (int b = wv; b < NB; b += 4) {
    const int ls = sstart[b], le = cur[b];
    const int gbase = goff[b];
    for (int e = ls + lane; e < le; e += 64) ebuf[gbase + (e - ls)] = stage[e];
  }
}

// ---- per-bucket CSR segment build via LDS staging, coalesced final write ----
__global__ __launch_bounds__(256) void csr_bucket(const unsigned* __restrict__ ebuf,
                                                  const int* __restrict__ offsets,
                                                  int* __restrict__ row_start,
                                                  int* __restrict__ csr_src,
                                                  int n, int E, int NBLK, int NB) {
  __shared__ unsigned stage[BCAP];       // 48 KB
  __shared__ int deg[256], cur[256];
  __shared__ int wtot[4];
  const int b = blockIdx.x;
  const int base = b << 8;
  const int nn = min(256, n - base);
  const int estart = offsets[b * NBLK];
  const int eend = (b + 1 < NB) ? offsets[(b + 1) * NBLK] : E;
  const int gstart = estart + base;
  const int tid = threadIdx.x;
  const int lane = tid & 63, wv = tid >> 6;
  deg[tid] = (tid < nn) ? 1 : 0;
  __syncthreads();
  for (int j = estart + tid; j < eend; j += 256) atomicAdd(&deg[ebuf[j] & 255u], 1);
  __syncthreads();
  int v = deg[tid];
  int x = v;
#pragma unroll
  for (int off = 1; off < 64; off <<= 1) {
    int y = __shfl_up(x, off);
    if (lane >= off) x += y;
  }
  if (lane == 63) wtot[wv] = x;
  __syncthreads();
  int add = 0;
  for (int w = 0; w < wv; ++w) add += wtot[w];
  int excl = x - v + add;
  cur[tid] = excl;
  if (tid < nn) row_start[base + tid] = gstart + excl;
  if (b == 0 && tid == 0) row_start[n] = E + n;
  __syncthreads();
  if (tid < nn) {
    int p = atomicAdd(&cur[tid], 1);
    if (p < BCAP) stage[p] = (unsigned)(base + tid);
    else csr_src[gstart + p] = base + tid;
  }
  for (int j = estart + tid; j < eend; j += 256) {
    unsigned pk = ebuf[j];
    int p = atomicAdd(&cur[pk & 255u], 1);
    if (p < BCAP) stage[p] = pk >> 8;
    else csr_src[gstart + p] = (int)(pk >> 8);
  }
  __syncthreads();
  const int tot = min(eend - estart + nn, BCAP);
  for (int e = tid; e < tot; e += 256) csr_src[gstart + e] = (int)stage[e];
}

// ====== MFMA projection GEMM + fused attn scores; LDS-staged coalesced P stores ======
template<int IC, int OC, int H, bool BN, bool AF32>
__global__ void gemm_mfma(const unsigned short* __restrict__ Act,
                          const float* __restrict__ Axf,
                          const unsigned short* __restrict__ Wt,
                          const float* __restrict__ a_s, const float* __restrict__ a_d,
                          const float* __restrict__ bnsums, const float* __restrict__ g,
                          const float* __restrict__ be,
                          unsigned short* __restrict__ Pb, float* __restrict__ es,
                          float* __restrict__ ed, int n) {
  constexpr int NF = OC / 16;                  // column fragments
  __shared__ float s_sc[IC], s_sf[IC];
  __shared__ unsigned short s_stage[4 * 16 * OC];
  const int tid = threadIdx.x;                 // 256 = 4 waves; wave covers 16 rows
  if (BN) {
    const float inv_n = 1.f / (float)n;
    for (int c = tid; c < IC; c += 256) {
      float mu = bnsums[c] * inv_n;
      float var = bnsums[IC + c] * inv_n - mu * mu;
      float s = g[c] * rsqrtf(var + BN_EPS);
      s_sc[c] = s;
      s_sf[c] = be[c] - mu * s;
    }
    __syncthreads();
  }
  const int lane = tid & 63;
  const int l15 = lane & 15;
  const int lk = lane >> 4;                    // 0..3
  const int wid = tid >> 6;
  const int node0 = blockIdx.x * 64 + wid * 16;
  const int arow = node0 + l15;
  const int ar = AF32 ? min(arow, n - 1) : arow;

  f32x4 acc[NF];
#pragma unroll
  for (int cb = 0; cb < NF; ++cb) acc[cb] = (f32x4){0.f, 0.f, 0.f, 0.f};

#pragma unroll
  for (int kc = 0; kc < IC / 32; ++kc) {
    const int kbase = kc * 32 + lk * 8;
    short8 a;
    if (AF32) {
      float4 u0 = *(const float4*)(Axf + (size_t)ar * IC + kbase);
      float4 u1 = *(const float4*)(Axf + (size_t)ar * IC + kbase + 4);
      a[0] = (short)f2bf(u0.x); a[1] = (short)f2bf(u0.y);
      a[2] = (short)f2bf(u0.z); a[3] = (short)f2bf(u0.w);
      a[4] = (short)f2bf(u1.x); a[5] = (short)f2bf(u1.y);
      a[6] = (short)f2bf(u1.z); a[7] = (short)f2bf(u1.w);
    } else {
      a = *(const short8*)(Act + (size_t)ar * IC + kbase);
    }
    if (BN) {
      short8 ta;
#pragma unroll
      for (int i = 0; i < 8; ++i) {
        float v = bf2f((unsigned short)a[i]);
        float y = fmaf(v, s_sc[kbase + i], s_sf[kbase + i]);
        y = (y > 0.f) ? y : (__expf(y) - 1.f);
        ta[i] = (short)f2bf(y);
      }
      a = ta;
    }
#pragma unroll
    for (int cb = 0; cb < NF; ++cb) {
      short8 b = *(const short8*)(Wt + (size_t)(cb * 16 + l15) * IC + kbase);
      acc[cb] = __builtin_amdgcn_mfma_f32_16x16x32_bf16(a, b, acc[cb], 0, 0, 0);
    }
  }

  // epilogue: fused es/ed scores + stage P into per-wave LDS tile
  unsigned short* st = s_stage + wid * 16 * OC;
  float esum[4] = {0.f, 0.f, 0.f, 0.f}, edum[4] = {0.f, 0.f, 0.f, 0.f};
#pragma unroll
  for (int cb = 0; cb < NF; ++cb) {
    const int j = cb * 16 + l15;
    const float asv = a_s[j];
    const float adv = a_d[j];
#pragma unroll
    for (int i = 0; i < 4; ++i) {
      float p = acc[cb][i];
      st[(lk * 4 + i) * OC + j] = f2bf(p);
      float ps = p * asv, pd = p * adv;
#pragma unroll
      for (int mm = 1; mm <= 8; mm <<= 1) {
        ps += __shfl_xor(ps, mm);
        pd += __shfl_xor(pd, mm);
      }
      esum[i] += ps;
      edum[i] += pd;
    }
    if (cb & 1) {
      const int h = cb >> 1;
#pragma unroll
      for (int i = 0; i < 4; ++i) {
        int node = node0 + lk * 4 + i;
        if (l15 == 0 && node < n) {
          es[node * H + h] = esum[i];
          ed[node * H + h] = edum[i];
        }
        esum[i] = 0.f;
        edum[i] = 0.f;
      }
    }
  }
  // coalesced P store (wave-synchronous LDS reuse; same wave wrote st)
  for (int idx = lane; idx < 2 * OC; idx += 64) {     // 16 rows * OC/8 uint4
    int r = idx / (OC / 8);
    int q = idx % (OC / 8);
    int node = node0 + r;
    if (node < n)
      *(uint4*)(Pb + (size_t)node * OC + q * 8) = *(const uint4*)(st + r * OC + q * 8);
  }
}

// ======== fused softmax + weighted gather + slotted BN-stat partials ========
template<int H, int C>
__global__ void node_agg(const int* __restrict__ row_start, const int* __restrict__ csr_src,
                         const float* __restrict__ es, const float* __restrict__ ed,
                         const unsigned short* __restrict__ Pb, unsigned short* __restrict__ Ob,
                         float* __restrict__ sums_part, int n) {
  constexpr int HC = H * C;
  constexpr int TPN = HC / 8;                  // threads per node (8 bf16 = 16 B each)
  __shared__ float ls[2 * HC];
  const int tid = threadIdx.x;                 // blockDim = 256
  for (int i = tid; i < 2 * HC; i += 256) ls[i] = 0.f;
  __syncthreads();
  const int t = tid % TPN;
  const int node = blockIdx.x * (256 / TPN) + tid / TPN;
  if (node < n) {
    const int h = (t * 8) / C;
    const int e0 = row_start[node];
    const int e1 = row_start[node + 1];
    const float edd = ed[node * H + h];
    const uint4* P4 = (const uint4*)Pb;
    float a0 = 0.f, a1 = 0.f, a2 = 0.f, a3 = 0.f;
    float a4 = 0.f, a5 = 0.f, a6 = 0.f, a7 = 0.f;
    float den = 0.f;
    int s0 = csr_src[e0];                      // deg >= 1 (self loop)
    int s1 = (e0 + 1 < e1) ? csr_src[e0 + 1] : s0;
    int s2 = (e0 + 2 < e1) ? csr_src[e0 + 2] : s0;
    int s3 = (e0 + 3 < e1) ? csr_src[e0 + 3] : s0;
    for (int j = e0; j < e1; j += 4) {
      const int nj = j + 4;
      int t0 = (nj     < e1) ? csr_src[nj]     : s0;
      int t1 = (nj + 1 < e1) ? csr_src[nj + 1] : s0;
      int t2 = (nj + 2 < e1) ? csr_src[nj + 2] : s0;
      int t3 = (nj + 3 < e1) ? csr_src[nj + 3] : s0;
      float x0 = es[s0 * H + h], x1 = es[s1 * H + h];
      float x2 = es[s2 * H + h], x3 = es[s3 * H + h];
      uint4 p0 = P4[(size_t)s0 * TPN + t];
      uint4 p1 = P4[(size_t)s1 * TPN + t];
      uint4 p2 = P4[(size_t)s2 * TPN + t];
      uint4 p3 = P4[(size_t)s3 * TPN + t];
      x0 += edd; x0 = fmaxf(x0, SLOPE * x0);
      x1 += edd; x1 = fmaxf(x1, SLOPE * x1);
      x2 += edd; x2 = fmaxf(x2, SLOPE * x2);
      x3 += edd; x3 = fmaxf(x3, SLOPE * x3);
      float w0 = __expf(x0);
      float w1 = (j + 1 < e1) ? __expf(x1) : 0.f;
      float w2 = (j + 2 < e1) ? __expf(x2) : 0.f;
      float w3 = (j + 3 < e1) ? __expf(x3) : 0.f;
      den += (w0 + w1) + (w2 + w3);
      a0 = fmaf(w0, __uint_as_float(p0.x << 16), a0);
      a1 = fmaf(w0, __uint_as_float(p0.x & 0xffff0000u), a1);
      a2 = fmaf(w0, __uint_as_float(p0.y << 16), a2);
      a3 = fmaf(w0, __uint_as_float(p0.y & 0xffff0000u), a3);
      a4 = fmaf(w0, __uint_as_float(p0.z << 16), a4);
      a5 = fmaf(w0, __uint_as_float(p0.z & 0xffff0000u), a5);
      a6 = fmaf(w0, __uint_as_float(p0.w << 16), a6);
      a7 = fmaf(w0, __uint_as_float(p0.w & 0xffff0000u), a7);
      a0 = fmaf(w1, __uint_as_float(p1.x << 16), a0);
      a1 = fmaf(w1, __uint_as_float(p1.x & 0xffff0000u), a1);
      a2 = fmaf(w1, __uint_as_float(p1.y << 16), a2);
      a3 = fmaf(w1, __uint_as_float(p1.y & 0xffff0000u), a3);
      a4 = fmaf(w1, __uint_as_float(p1.z << 16), a4);
      a5 = fmaf(w1, __uint_as_float(p1.z & 0xffff0000u), a5);
      a6 = fmaf(w1, __uint_as_float(p1.w << 16), a6);
      a7 = fmaf(w1, __uint_as_float(p1.w & 0xffff0000u), a7);
      a0 = fmaf(w2, __uint_as_float(p2.x << 16), a0);
      a1 = fmaf(w2, __uint_as_float(p2.x & 0xffff0000u), a1);
      a2 = fmaf(w2, __uint_as_float(p2.y << 16), a2);
      a3 = fmaf(w2, __uint_as_float(p2.y & 0xffff0000u), a3);
      a4 = fmaf(w2, __uint_as_float(p2.z << 16), a4);
      a5 = fmaf(w2, __uint_as_float(p2.z & 0xffff0000u), a5);
      a6 = fmaf(w2, __uint_as_float(p2.w << 16), a6);
      a7 = fmaf(w2, __uint_as_float(p2.w & 0xffff0000u), a7);
      a0 = fmaf(w3, __uint_as_float(p3.x << 16), a0);
      a1 = fmaf(w3, __uint_as_float(p3.x & 0xffff0000u), a1);
      a2 = fmaf(w3, __uint_as_float(p3.y << 16), a2);
      a3 = fmaf(w3, __uint_as_float(p3.y & 0xffff0000u), a3);
      a4 = fmaf(w3, __uint_as_float(p3.z << 16), a4);
      a5 = fmaf(w3, __uint_as_float(p3.z & 0xffff0000u), a5);
      a6 = fmaf(w3, __uint_as_float(p3.w << 16), a6);
      a7 = fmaf(w3, __uint_as_float(p3.w & 0xffff0000u), a7);
      s0 = t0; s1 = t1; s2 = t2; s3 = t3;
    }
    float inv = 1.f / (den + 1e-16f);
    a0 *= inv; a1 *= inv; a2 *= inv; a3 *= inv;
    a4 *= inv; a5 *= inv; a6 *= inv; a7 *= inv;
    const int c0 = t * 8;
    atomicAdd(&ls[c0 + 0], a0); atomicAdd(&ls[HC + c0 + 0], a0 * a0);
    atomicAdd(&ls[c0 + 1], a1); atomicAdd(&ls[HC + c0 + 1], a1 * a1);
    atomicAdd(&ls[c0 + 2], a2); atomicAdd(&ls[HC + c0 + 2], a2 * a2);
    atomicAdd(&ls[c0 + 3], a3); atomicAdd(&ls[HC + c0 + 3], a3 * a3);
    atomicAdd(&ls[c0 + 4], a4); atomicAdd(&ls[HC + c0 + 4], a4 * a4);
    atomicAdd(&ls[c0 + 5], a5); atomicAdd(&ls[HC + c0 + 5], a5 * a5);
    atomicAdd(&ls[c0 + 6], a6); atomicAdd(&ls[HC + c0 + 6], a6 * a6);
    atomicAdd(&ls[c0 + 7], a7); atomicAdd(&ls[HC + c0 + 7], a7 * a7);
    uint4 o;
    o.x = (unsigned)f2bf(a0) | ((unsigned)f2bf(a1) << 16);
    o.y = (unsigned)f2bf(a2) | ((unsigned)f2bf(a3) << 16);
    o.z = (unsigned)f2bf(a4) | ((unsigned)f2bf(a5) << 16);
    o.w = (unsigned)f2bf(a6) | ((unsigned)f2bf(a7) << 16);
    *(uint4*)(Ob + (size_t)node * HC + t * 8) = o;
  }
  __syncthreads();
  float* dst = sums_part + (size_t)(blockIdx.x & 63) * (2 * HC);
  for (int i = tid; i < 2 * HC; i += 256) unsafeAtomicAdd(&dst[i], ls[i]);
}

// ============ fold 64 BN partial slots -> final sums (1 block) ============
template<int C>
__global__ void finalize_bn(const float* __restrict__ part, float* __restrict__ sums) {
  const int tid = threadIdx.x;                 // 256
  for (int c = tid; c < 2 * C; c += 256) {
    float s = 0.f;
    for (int k = 0; k < 64; ++k) s += part[(size_t)k * 2 * C + c];
    sums[c] = s;
  }
}

// ================= final MLP with fused BN+ELU on bf16 load =================
__global__ void mlp_head(const unsigned short* __restrict__ Hf, const float* __restrict__ bnsums,
                         const float* __restrict__ g, const float* __restrict__ be,
                         const float* __restrict__ cw1, const float* __restrict__ cb1,
                         const float* __restrict__ cw2, const float* __restrict__ cb2,
                         float* __restrict__ out, int n) {
  __shared__ float w1[32 * 16];
  __shared__ float b1[16];
  __shared__ float w2[16 * 2];
  __shared__ float b2[2];
  __shared__ float sc[32], sf[32];
  int tid = threadIdx.x;
  for (int i = tid; i < 32 * 16; i += blockDim.x) w1[i] = cw1[i];
  if (tid < 16) b1[tid] = cb1[tid];
  if (tid < 32) w2[tid] = cw2[tid];
  if (tid < 2) b2[tid] = cb2[tid];
  if (tid < 32) {
    float inv_n = 1.f / (float)n;
    float mu = bnsums[tid] * inv_n;
    float var = bnsums[32 + tid] * inv_n - mu * mu;
    float s = g[tid] * rsqrtf(var + BN_EPS);
    sc[tid] = s;
    sf[tid] = be[tid] - mu * s;
  }
  __syncthreads();
  int node = blockIdx.x * blockDim.x + tid;
  if (node >= n) return;
  float x[32];
  const uint4* xp = (const uint4*)(Hf + (size_t)node * 32);
#pragma unroll
  for (int q = 0; q < 4; ++q) {
    uint4 v = xp[q];
    unsigned pr[4] = {v.x, v.y, v.z, v.w};
#pragma unroll
    for (int u = 0; u < 4; ++u) {
      int c = q * 8 + u * 2;
      float va = __uint_as_float(pr[u] << 16);
      float vb = __uint_as_float(pr[u] & 0xffff0000u);
      float ya = fmaf(va, sc[c], sf[c]);
      float yb = fmaf(vb, sc[c + 1], sf[c + 1]);
      x[c] = (ya > 0.f) ? ya : (__expf(ya) - 1.f);
      x[c + 1] = (yb > 0.f) ? yb : (__expf(yb) - 1.f);
    }
  }
  float o0 = b2[0], o1 = b2[1];
#pragma unroll
  for (int j = 0; j < 16; ++j) {
    float acc = b1[j];
#pragma unroll
    for (int k = 0; k < 32; ++k) acc = fmaf(x[k], w1[k * 16 + j], acc);
    acc = (acc > 0.f) ? acc : (__expf(acc) - 1.f);
    o0 = fmaf(acc, w2[j * 2 + 0], o0);
    o1 = fmaf(acc, w2[j * 2 + 1], o1);
  }
  out[(size_t)node * 2 + 0] = o0;
  out[(size_t)node * 2 + 1] = o1;
}

extern "C" void kernel_launch(void* const* d_in, const int* in_sizes, int n_in,
                              void* d_out, int out_size, void* d_ws, size_t ws_size,
                              hipStream_t stream) {
  const float* x   = (const float*)d_in[0];
  const int*   ei  = (const int*)d_in[1];
  const float* W0  = (const float*)d_in[2];
  const float* as0 = (const float*)d_in[3];
  const float* ad0 = (const float*)d_in[4];
  const float* g0  = (const float*)d_in[6];
  const float* be0 = (const float*)d_in[7];
  const float* W1  = (const float*)d_in[8];
  const float* as1 = (const float*)d_in[9];
  const float* ad1 = (const float*)d_in[10];
  const float* g1  = (const float*)d_in[12];
  const float* be1 = (const float*)d_in[13];
  const float* W2  = (const float*)d_in[14];
  const float* as2 = (const float*)d_in[15];
  const float* ad2 = (const float*)d_in[16];
  const float* g2  = (const float*)d_in[18];
  const float* be2 = (const float*)d_in[19];
  const float* cw1 = (const float*)d_in[20];
  const float* cb1 = (const float*)d_in[21];
  const float* cw2 = (const float*)d_in[22];
  const float* cb2 = (const float*)d_in[23];
  // b0/b1/b2 cancel in the following BatchNorm -> skipped.

  const int n = in_sizes[0] / 128;
  const int E = in_sizes[1] / 2;
  const int n64 = cdiv(n, 64) * 64;

  const int NBLK = cdiv(E, EPB);
  const int NB = cdiv(n, 256);
  const int m = NB * NBLK;

  // ---- workspace layout ----
  unsigned short* Ab  = (unsigned short*)d_ws;            // n64*128
  unsigned short* Bb  = Ab + (size_t)n64 * 128;           // n64*128
  unsigned short* Pb  = Bb + (size_t)n64 * 128;           // n64*128
  unsigned short* Af  = Pb + (size_t)n64 * 128;           // n64*32
  unsigned short* Wt0 = Af + (size_t)n64 * 32;            // 128*128
  unsigned short* Wt1 = Wt0 + 128 * 128;                  // 128*128
  unsigned short* Wt2 = Wt1 + 128 * 128;                  // 32*128
  float* es    = (float*)(Wt2 + 32 * 128);                // n*4
  float* ed    = es + (size_t)n * 4;                      // n*4
  float* sums0 = ed + (size_t)n * 4;                      // 256
  float* sums1 = sums0 + 256;                             // 256
  float* sums2 = sums1 + 256;                             // 64
  float* SP0   = sums2 + 64;                              // 64*256
  float* SP1   = SP0 + 64 * 256;                          // 64*256
  float* SP2   = SP1 + 64 * 256;                          // 64*64
  int* counts    = (int*)(SP2 + 64 * 64);                 // m
  int* offsets   = counts + m;                            // m+1
  int* row_start = offsets + m + 1;                       // n+1
  int* csr_src   = row_start + n + 1;                     // E+n
  unsigned* ebuf = (unsigned*)(csr_src + E + n);          // E

  // ===== CSR build + weight prep + slot zeroing =====
  prep_hist<<<NBLK + 192, 256, 0, stream>>>(ei, counts, W0, W1, W2, Wt0, Wt1, Wt2,
                                            SP0, SP1, SP2, E, NBLK, NB);
  csr_scan2<<<1, 1024, 0, stream>>>(counts, offsets, m);
  csr_part<<<NBLK, 256, 0, stream>>>(ei, offsets, ebuf, E, NBLK, NB);
  csr_bucket<<<NB, 256, 0, stream>>>(ebuf, offsets, row_start, csr_src, n, E, NBLK, NB);

  // ===== layer 0 (fp32 x read directly) =====
  gemm_mfma<128, 128, 4, false, true><<<cdiv(n, 64), 256, 0, stream>>>(
      nullptr, x, Wt0, as0, ad0, nullptr, nullptr, nullptr, Pb, es, ed, n);
  node_agg<4, 32><<<cdiv(n, 16), 256, 0, stream>>>(row_start, csr_src, es, ed, Pb, Ab, SP0, n);
  finalize_bn<128><<<1, 256, 0, stream>>>(SP0, sums0);

  // ===== layer 1 (BN+ELU fused on load) =====
  gemm_mfma<128, 128, 4, true, false><<<cdiv(n, 64), 256, 0, stream>>>(
      Ab, nullptr, Wt1, as1, ad1, sums0, g0, be0, Pb, es, ed, n);
  node_agg<4, 32><<<cdiv(n, 16), 256, 0, stream>>>(row_start, csr_src, es, ed, Pb, Bb, SP1, n);
  finalize_bn<128><<<1, 256, 0, stream>>>(SP1, sums1);

  // ===== layer 2 =====
  gemm_mfma<128, 32, 1, true, false><<<cdiv(n, 64), 256, 0, stream>>>(
      Bb, nullptr, Wt2, as2, ad2, sums1, g1, be1, Pb, es, ed, n);
  node_agg<1, 32><<<cdiv(n, 64), 256, 0, stream>>>(row_start, csr_src, es, ed, Pb, Af, SP2, n);
  finalize_bn<32><<<1, 256, 0, stream>>>(SP2, sums2);

  // ===== head MLP with fused BN+ELU =====
  mlp_head<<<cdiv(n, 256), 256, 0, stream>>>(Af, sums2, g2, be2, cw1, cb1, cw2, cb2,
                                             (float*)d_out, n);
}

// Round 11
// 423.305 us; speedup vs baseline: 1.0910x; 1.0910x over previous
//
#include <hip/hip_runtime.h>

static constexpr float SLOPE = 0.2f;
static constexpr float BN_EPS = 1e-5f;

static inline int cdiv(long long a, long long b) { return (int)((a + b - 1) / b); }

typedef __attribute__((ext_vector_type(8))) short short8;
typedef __attribute__((ext_vector_type(4))) float f32x4;

__device__ __forceinline__ unsigned short f2bf(float f) {
  unsigned u = __float_as_uint(f);
  u += 0x7fff + ((u >> 16) & 1);          // round-to-nearest-even
  return (unsigned short)(u >> 16);
}
__device__ __forceinline__ float bf2f(unsigned short h) {
  return __uint_as_float((unsigned)h << 16);
}

// ====================== CSR build: bucket-partitioned, LDS-staged ======================
static constexpr int EPB = 8192;        // edges per partition block
static constexpr int BCAP = 12288;      // LDS staging capacity in csr_bucket

// ---- merged: per-block bucket histogram + weight transpose + bn-sum zeroing ----
// grid = NBLK + 145
__global__ void prep_hist(const int* __restrict__ ei, int* __restrict__ counts,
                          const float* __restrict__ W0, const float* __restrict__ W1,
                          const float* __restrict__ W2,
                          unsigned short* __restrict__ Wt0, unsigned short* __restrict__ Wt1,
                          unsigned short* __restrict__ Wt2,
                          float* __restrict__ sums0, float* __restrict__ sums1,
                          float* __restrict__ sums2,
                          int E, int NBLK, int NB) {
  const int tid = threadIdx.x;
  const int blk = blockIdx.x;
  if (blk < NBLK) {                      // histogram role
    __shared__ int cnt[256];
    cnt[tid] = 0;
    __syncthreads();
    const int i0 = blk * EPB;
    const int i1 = min(E, i0 + EPB);
    for (int i = i0 + tid; i < i1; i += 256) atomicAdd(&cnt[ei[E + i] >> 8], 1);
    __syncthreads();
    if (tid < NB) counts[tid * NBLK + blk] = cnt[tid];
    return;
  }
  const int b = blk - NBLK;
  if (b < 64) {                          // Wt0[j][k] = W0[k][j], 128x128
    int o = b * 256 + tid;
    int j = o >> 7, k = o & 127;
    Wt0[o] = f2bf(W0[k * 128 + j]);
  } else if (b < 128) {
    int o = (b - 64) * 256 + tid;
    int j = o >> 7, k = o & 127;
    Wt1[o] = f2bf(W1[k * 128 + j]);
  } else if (b < 144) {                  // Wt2[j][k] = W2[k][j], 32x128
    int o = (b - 128) * 256 + tid;
    int j = o >> 7, k = o & 127;
    Wt2[o] = f2bf(W2[k * 32 + j]);
  } else {
    sums0[tid] = 0.f;
    sums1[tid] = 0.f;
    if (tid < 64) sums2[tid] = 0.f;
  }
}

// ---- chunked 2-pass exclusive scan, single block of 1024 ----
__global__ void csr_scan2(const int* __restrict__ counts, int* __restrict__ offsets, int m) {
  __shared__ int wtot[16];
  const int tid = threadIdx.x;
  const int lane = tid & 63, wv = tid >> 6;
  const int CH = (m + 1023) >> 10;
  const int lo = min(m, tid * CH);
  const int hi = min(m, lo + CH);
  int sum = 0;
  for (int i = lo; i < hi; ++i) sum += counts[i];
  int x = sum;
#pragma unroll
  for (int off = 1; off < 64; off <<= 1) {
    int y = __shfl_up(x, off);
    if (lane >= off) x += y;
  }
  if (lane == 63) wtot[wv] = x;
  __syncthreads();
  int add = 0;
  for (int w = 0; w < wv; ++w) add += wtot[w];
  int run = x - sum + add;
  for (int i = lo; i < hi; ++i) { offsets[i] = run; run += counts[i]; }
  if (hi == m) offsets[m] = run;
}

// ---- partition edges into bucket-major packed runs via LDS staging ----
__global__ __launch_bounds__(256) void csr_part(const int* __restrict__ ei,
                                                const int* __restrict__ offsets,
                                                unsigned* __restrict__ ebuf,
                                                int E, int NBLK, int NB) {
  __shared__ unsigned stage[EPB];        // 32 KB
  __shared__ int cnt[256], sstart[256], cur[256], goff[256];
  __shared__ int wtot[4];
  const int tid = threadIdx.x;
  const int blk = blockIdx.x;
  const int lane = tid & 63, wv = tid >> 6;
  cnt[tid] = 0;
  if (tid < NB) goff[tid] = offsets[tid * NBLK + blk];
  __syncthreads();
  const int i0 = blk * EPB;
  const int i1 = min(E, i0 + EPB);
  for (int i = i0 + tid; i < i1; i += 256) atomicAdd(&cnt[ei[E + i] >> 8], 1);
  __syncthreads();
  int v = cnt[tid];
  int x = v;
#pragma unroll
  for (int off = 1; off < 64; off <<= 1) {
    int y = __shfl_up(x, off);
    if (lane >= off) x += y;
  }
  if (lane == 63) wtot[wv] = x;
  __syncthreads();
  int add = 0;
  for (int w = 0; w < wv; ++w) add += wtot[w];
  int excl = x - v + add;
  sstart[tid] = excl;
  cur[tid] = excl;
  __syncthreads();
  for (int i = i0 + tid; i < i1; i += 256) {
    int s = ei[i], d = ei[E + i];
    int p = atomicAdd(&cur[d >> 8], 1);
    stage[p] = ((unsigned)s << 8) | (unsigned)(d & 255);
  }
  __syncthreads();
  for (int b = wv; b < NB; b += 4) {
    const int ls = sstart[b], le = cur[b];
    const int gbase = goff[b];
    for (int e = ls + lane; e < le; e += 64) ebuf[gbase + (e - ls)] = stage[e];
  }
}

// ---- per-bucket CSR segment build via LDS staging, coalesced final write ----
__global__ __launch_bounds__(256) void csr_bucket(const unsigned* __restrict__ ebuf,
                                                  const int* __restrict__ offsets,
                                                  int* __restrict__ row_start,
                                                  int* __restrict__ csr_src,
                                                  int n, int E, int NBLK, int NB) {
  __shared__ unsigned stage[BCAP];       // 48 KB
  __shared__ int deg[256], cur[256];
  __shared__ int wtot[4];
  const int b = blockIdx.x;
  const int base = b << 8;
  const int nn = min(256, n - base);
  const int estart = offsets[b * NBLK];
  const int eend = (b + 1 < NB) ? offsets[(b + 1) * NBLK] : E;
  const int gstart = estart + base;
  const int tid = threadIdx.x;
  const int lane = tid & 63, wv = tid >> 6;
  deg[tid] = (tid < nn) ? 1 : 0;
  __syncthreads();
  for (int j = estart + tid; j < eend; j += 256) atomicAdd(&deg[ebuf[j] & 255u], 1);
  __syncthreads();
  int v = deg[tid];
  int x = v;
#pragma unroll
  for (int off = 1; off < 64; off <<= 1) {
    int y = __shfl_up(x, off);
    if (lane >= off) x += y;
  }
  if (lane == 63) wtot[wv] = x;
  __syncthreads();
  int add = 0;
  for (int w = 0; w < wv; ++w) add += wtot[w];
  int excl = x - v + add;
  cur[tid] = excl;
  if (tid < nn) row_start[base + tid] = gstart + excl;
  if (b == 0 && tid == 0) row_start[n] = E + n;
  __syncthreads();
  if (tid < nn) {
    int p = atomicAdd(&cur[tid], 1);
    if (p < BCAP) stage[p] = (unsigned)(base + tid);
    else csr_src[gstart + p] = base + tid;
  }
  for (int j = estart + tid; j < eend; j += 256) {
    unsigned pk = ebuf[j];
    int p = atomicAdd(&cur[pk & 255u], 1);
    if (p < BCAP) stage[p] = pk >> 8;
    else csr_src[gstart + p] = (int)(pk >> 8);
  }
  __syncthreads();
  const int tot = min(eend - estart + nn, BCAP);
  for (int e = tid; e < tot; e += 256) csr_src[gstart + e] = (int)stage[e];
}

// ====== MFMA projection GEMM + fused attn scores; LDS-staged coalesced P stores ======
template<int IC, int OC, int H, bool BN, bool AF32>
__global__ void gemm_mfma(const unsigned short* __restrict__ Act,
                          const float* __restrict__ Axf,
                          const unsigned short* __restrict__ Wt,
                          const float* __restrict__ a_s, const float* __restrict__ a_d,
                          const float* __restrict__ bnsums, const float* __restrict__ g,
                          const float* __restrict__ be,
                          unsigned short* __restrict__ Pb, float* __restrict__ es,
                          float* __restrict__ ed, int n) {
  constexpr int NF = OC / 16;                  // column fragments
  __shared__ float s_sc[IC], s_sf[IC];
  __shared__ unsigned short s_stage[4 * 16 * OC];
  const int tid = threadIdx.x;                 // 256 = 4 waves; wave covers 16 rows
  if (BN) {
    const float inv_n = 1.f / (float)n;
    for (int c = tid; c < IC; c += 256) {
      float mu = bnsums[c] * inv_n;
      float var = bnsums[IC + c] * inv_n - mu * mu;
      float s = g[c] * rsqrtf(var + BN_EPS);
      s_sc[c] = s;
      s_sf[c] = be[c] - mu * s;
    }
    __syncthreads();
  }
  const int lane = tid & 63;
  const int l15 = lane & 15;
  const int lk = lane >> 4;                    // 0..3
  const int wid = tid >> 6;
  const int node0 = blockIdx.x * 64 + wid * 16;
  const int arow = node0 + l15;
  const int ar = AF32 ? min(arow, n - 1) : arow;

  f32x4 acc[NF];
#pragma unroll
  for (int cb = 0; cb < NF; ++cb) acc[cb] = (f32x4){0.f, 0.f, 0.f, 0.f};

#pragma unroll
  for (int kc = 0; kc < IC / 32; ++kc) {
    const int kbase = kc * 32 + lk * 8;
    short8 a;
    if (AF32) {
      float4 u0 = *(const float4*)(Axf + (size_t)ar * IC + kbase);
      float4 u1 = *(const float4*)(Axf + (size_t)ar * IC + kbase + 4);
      a[0] = (short)f2bf(u0.x); a[1] = (short)f2bf(u0.y);
      a[2] = (short)f2bf(u0.z); a[3] = (short)f2bf(u0.w);
      a[4] = (short)f2bf(u1.x); a[5] = (short)f2bf(u1.y);
      a[6] = (short)f2bf(u1.z); a[7] = (short)f2bf(u1.w);
    } else {
      a = *(const short8*)(Act + (size_t)ar * IC + kbase);
    }
    if (BN) {
      short8 ta;
#pragma unroll
      for (int i = 0; i < 8; ++i) {
        float v = bf2f((unsigned short)a[i]);
        float y = fmaf(v, s_sc[kbase + i], s_sf[kbase + i]);
        y = (y > 0.f) ? y : (__expf(y) - 1.f);
        ta[i] = (short)f2bf(y);
      }
      a = ta;
    }
#pragma unroll
    for (int cb = 0; cb < NF; ++cb) {
      short8 b = *(const short8*)(Wt + (size_t)(cb * 16 + l15) * IC + kbase);
      acc[cb] = __builtin_amdgcn_mfma_f32_16x16x32_bf16(a, b, acc[cb], 0, 0, 0);
    }
  }

  // epilogue: fused es/ed scores + stage P into per-wave LDS tile
  unsigned short* st = s_stage + wid * 16 * OC;
  float esum[4] = {0.f, 0.f, 0.f, 0.f}, edum[4] = {0.f, 0.f, 0.f, 0.f};
#pragma unroll
  for (int cb = 0; cb < NF; ++cb) {
    const int j = cb * 16 + l15;
    const float asv = a_s[j];
    const float adv = a_d[j];
#pragma unroll
    for (int i = 0; i < 4; ++i) {
      float p = acc[cb][i];
      st[(lk * 4 + i) * OC + j] = f2bf(p);
      float ps = p * asv, pd = p * adv;
#pragma unroll
      for (int mm = 1; mm <= 8; mm <<= 1) {
        ps += __shfl_xor(ps, mm);
        pd += __shfl_xor(pd, mm);
      }
      esum[i] += ps;
      edum[i] += pd;
    }
    if (cb & 1) {
      const int h = cb >> 1;
#pragma unroll
      for (int i = 0; i < 4; ++i) {
        int node = node0 + lk * 4 + i;
        if (l15 == 0 && node < n) {
          es[node * H + h] = esum[i];
          ed[node * H + h] = edum[i];
        }
        esum[i] = 0.f;
        edum[i] = 0.f;
      }
    }
  }
  // coalesced P store (wave-synchronous LDS reuse; same wave wrote st)
  for (int idx = lane; idx < 2 * OC; idx += 64) {     // 16 rows * OC/8 uint4
    int r = idx / (OC / 8);
    int q = idx % (OC / 8);
    int node = node0 + r;
    if (node < n)
      *(uint4*)(Pb + (size_t)node * OC + q * 8) = *(const uint4*)(st + r * OC + q * 8);
  }
}

// ======== fused max-free softmax + weighted gather (unroll-4, 4-ahead prefetch) ========
// NOTE: barrier-free by design — per-wave independent progress; BN-stat fusion
// regressed twice (R6/R10) because a block-tail __syncthreads couples nodes to
// the max in-degree of the group. Keep stats in a separate streaming kernel.
template<int H, int C>
__global__ void node_agg(const int* __restrict__ row_start, const int* __restrict__ csr_src,
                         const float* __restrict__ es, const float* __restrict__ ed,
                         const unsigned short* __restrict__ Pb, unsigned short* __restrict__ Ob,
                         int n) {
  constexpr int HC = H * C;
  constexpr int TPN = HC / 8;                  // threads per node (8 bf16 = 16 B each)
  const int tid = threadIdx.x;                 // blockDim = 256
  const int t = tid % TPN;
  const int node = blockIdx.x * (256 / TPN) + tid / TPN;
  if (node >= n) return;
  const int h = (t * 8) / C;
  const int e0 = row_start[node];
  const int e1 = row_start[node + 1];
  const float edd = ed[node * H + h];
  const uint4* P4 = (const uint4*)Pb;
  float a0 = 0.f, a1 = 0.f, a2 = 0.f, a3 = 0.f;
  float a4 = 0.f, a5 = 0.f, a6 = 0.f, a7 = 0.f;
  float den = 0.f;
  int s0 = csr_src[e0];                        // deg >= 1 (self loop)
  int s1 = (e0 + 1 < e1) ? csr_src[e0 + 1] : s0;
  int s2 = (e0 + 2 < e1) ? csr_src[e0 + 2] : s0;
  int s3 = (e0 + 3 < e1) ? csr_src[e0 + 3] : s0;
  for (int j = e0; j < e1; j += 4) {
    const int nj = j + 4;
    int t0 = (nj     < e1) ? csr_src[nj]     : s0;
    int t1 = (nj + 1 < e1) ? csr_src[nj + 1] : s0;
    int t2 = (nj + 2 < e1) ? csr_src[nj + 2] : s0;
    int t3 = (nj + 3 < e1) ? csr_src[nj + 3] : s0;
    float x0 = es[s0 * H + h], x1 = es[s1 * H + h];
    float x2 = es[s2 * H + h], x3 = es[s3 * H + h];
    uint4 p0 = P4[(size_t)s0 * TPN + t];
    uint4 p1 = P4[(size_t)s1 * TPN + t];
    uint4 p2 = P4[(size_t)s2 * TPN + t];
    uint4 p3 = P4[(size_t)s3 * TPN + t];
    x0 += edd; x0 = fmaxf(x0, SLOPE * x0);
    x1 += edd; x1 = fmaxf(x1, SLOPE * x1);
    x2 += edd; x2 = fmaxf(x2, SLOPE * x2);
    x3 += edd; x3 = fmaxf(x3, SLOPE * x3);
    float w0 = __expf(x0);
    float w1 = (j + 1 < e1) ? __expf(x1) : 0.f;
    float w2 = (j + 2 < e1) ? __expf(x2) : 0.f;
    float w3 = (j + 3 < e1) ? __expf(x3) : 0.f;
    den += (w0 + w1) + (w2 + w3);
    a0 = fmaf(w0, __uint_as_float(p0.x << 16), a0);
    a1 = fmaf(w0, __uint_as_float(p0.x & 0xffff0000u), a1);
    a2 = fmaf(w0, __uint_as_float(p0.y << 16), a2);
    a3 = fmaf(w0, __uint_as_float(p0.y & 0xffff0000u), a3);
    a4 = fmaf(w0, __uint_as_float(p0.z << 16), a4);
    a5 = fmaf(w0, __uint_as_float(p0.z & 0xffff0000u), a5);
    a6 = fmaf(w0, __uint_as_float(p0.w << 16), a6);
    a7 = fmaf(w0, __uint_as_float(p0.w & 0xffff0000u), a7);
    a0 = fmaf(w1, __uint_as_float(p1.x << 16), a0);
    a1 = fmaf(w1, __uint_as_float(p1.x & 0xffff0000u), a1);
    a2 = fmaf(w1, __uint_as_float(p1.y << 16), a2);
    a3 = fmaf(w1, __uint_as_float(p1.y & 0xffff0000u), a3);
    a4 = fmaf(w1, __uint_as_float(p1.z << 16), a4);
    a5 = fmaf(w1, __uint_as_float(p1.z & 0xffff0000u), a5);
    a6 = fmaf(w1, __uint_as_float(p1.w << 16), a6);
    a7 = fmaf(w1, __uint_as_float(p1.w & 0xffff0000u), a7);
    a0 = fmaf(w2, __uint_as_float(p2.x << 16), a0);
    a1 = fmaf(w2, __uint_as_float(p2.x & 0xffff0000u), a1);
    a2 = fmaf(w2, __uint_as_float(p2.y << 16), a2);
    a3 = fmaf(w2, __uint_as_float(p2.y & 0xffff0000u), a3);
    a4 = fmaf(w2, __uint_as_float(p2.z << 16), a4);
    a5 = fmaf(w2, __uint_as_float(p2.z & 0xffff0000u), a5);
    a6 = fmaf(w2, __uint_as_float(p2.w << 16), a6);
    a7 = fmaf(w2, __uint_as_float(p2.w & 0xffff0000u), a7);
    a0 = fmaf(w3, __uint_as_float(p3.x << 16), a0);
    a1 = fmaf(w3, __uint_as_float(p3.x & 0xffff0000u), a1);
    a2 = fmaf(w3, __uint_as_float(p3.y << 16), a2);
    a3 = fmaf(w3, __uint_as_float(p3.y & 0xffff0000u), a3);
    a4 = fmaf(w3, __uint_as_float(p3.z << 16), a4);
    a5 = fmaf(w3, __uint_as_float(p3.z & 0xffff0000u), a5);
    a6 = fmaf(w3, __uint_as_float(p3.w << 16), a6);
    a7 = fmaf(w3, __uint_as_float(p3.w & 0xffff0000u), a7);
    s0 = t0; s1 = t1; s2 = t2; s3 = t3;
  }
  float inv = 1.f / (den + 1e-16f);
  uint4 o;
  o.x = (unsigned)f2bf(a0 * inv) | ((unsigned)f2bf(a1 * inv) << 16);
  o.y = (unsigned)f2bf(a2 * inv) | ((unsigned)f2bf(a3 * inv) << 16);
  o.z = (unsigned)f2bf(a4 * inv) | ((unsigned)f2bf(a5 * inv) << 16);
  o.w = (unsigned)f2bf(a6 * inv) | ((unsigned)f2bf(a7 * inv) << 16);
  *(uint4*)(Ob + (size_t)node * HC + t * 8) = o;
}

// ============ BN stats: LDS partials, uint2 loads, high occupancy ============
template<int C>
__global__ void bn_stats2(const unsigned short* __restrict__ X, float* __restrict__ sums,
                          int n) {
  constexpr int TPR = C / 4;                   // threads per row (4 bf16 each)
  constexpr int RPB = 256 / TPR;               // rows per block-iteration
  __shared__ float ls[2 * C];
  const int tid = threadIdx.x;
  for (int i = tid; i < 2 * C; i += 256) ls[i] = 0.f;
  __syncthreads();
  const int c4 = (tid % TPR) * 4;
  const int rb = tid / TPR;
  float s0 = 0.f, s1 = 0.f, s2 = 0.f, s3 = 0.f;
  float q0 = 0.f, q1 = 0.f, q2 = 0.f, q3 = 0.f;
  for (int r = blockIdx.x * RPB + rb; r < n; r += gridDim.x * RPB) {
    uint2 v = *(const uint2*)(X + (size_t)r * C + c4);
    float f0 = __uint_as_float(v.x << 16);
    float f1 = __uint_as_float(v.x & 0xffff0000u);
    float f2 = __uint_as_float(v.y << 16);
    float f3 = __uint_as_float(v.y & 0xffff0000u);
    s0 += f0; q0 = fmaf(f0, f0, q0);
    s1 += f1; q1 = fmaf(f1, f1, q1);
    s2 += f2; q2 = fmaf(f2, f2, q2);
    s3 += f3; q3 = fmaf(f3, f3, q3);
  }
  atomicAdd(&ls[c4 + 0], s0);
  atomicAdd(&ls[c4 + 1], s1);
  atomicAdd(&ls[c4 + 2], s2);
  atomicAdd(&ls[c4 + 3], s3);
  atomicAdd(&ls[C + c4 + 0], q0);
  atomicAdd(&ls[C + c4 + 1], q1);
  atomicAdd(&ls[C + c4 + 2], q2);
  atomicAdd(&ls[C + c4 + 3], q3);
  __syncthreads();
  for (int i = tid; i < 2 * C; i += 256) unsafeAtomicAdd(&sums[i], ls[i]);
}

// ================= final MLP with fused BN+ELU on bf16 load =================
__global__ void mlp_head(const unsigned short* __restrict__ Hf, const float* __restrict__ bnsums,
                         const float* __restrict__ g, const float* __restrict__ be,
                         const float* __restrict__ cw1, const float* __restrict__ cb1,
                         const float* __restrict__ cw2, const float* __restrict__ cb2,
                         float* __restrict__ out, int n) {
  __shared__ float w1[32 * 16];
  __shared__ float b1[16];
  __shared__ float w2[16 * 2];
  __shared__ float b2[2];
  __shared__ float sc[32], sf[32];
  int tid = threadIdx.x;
  for (int i = tid; i < 32 * 16; i += blockDim.x) w1[i] = cw1[i];
  if (tid < 16) b1[tid] = cb1[tid];
  if (tid < 32) w2[tid] = cw2[tid];
  if (tid < 2) b2[tid] = cb2[tid];
  if (tid < 32) {
    float inv_n = 1.f / (float)n;
    float mu = bnsums[tid] * inv_n;
    float var = bnsums[32 + tid] * inv_n - mu * mu;
    float s = g[tid] * rsqrtf(var + BN_EPS);
    sc[tid] = s;
    sf[tid] = be[tid] - mu * s;
  }
  __syncthreads();
  int node = blockIdx.x * blockDim.x + tid;
  if (node >= n) return;
  float x[32];
  const uint4* xp = (const uint4*)(Hf + (size_t)node * 32);
#pragma unroll
  for (int q = 0; q < 4; ++q) {
    uint4 v = xp[q];
    unsigned pr[4] = {v.x, v.y, v.z, v.w};
#pragma unroll
    for (int u = 0; u < 4; ++u) {
      int c = q * 8 + u * 2;
      float va = __uint_as_float(pr[u] << 16);
      float vb = __uint_as_float(pr[u] & 0xffff0000u);
      float ya = fmaf(va, sc[c], sf[c]);
      float yb = fmaf(vb, sc[c + 1], sf[c + 1]);
      x[c] = (ya > 0.f) ? ya : (__expf(ya) - 1.f);
      x[c + 1] = (yb > 0.f) ? yb : (__expf(yb) - 1.f);
    }
  }
  float o0 = b2[0], o1 = b2[1];
#pragma unroll
  for (int j = 0; j < 16; ++j) {
    float acc = b1[j];
#pragma unroll
    for (int k = 0; k < 32; ++k) acc = fmaf(x[k], w1[k * 16 + j], acc);
    acc = (acc > 0.f) ? acc : (__expf(acc) - 1.f);
    o0 = fmaf(acc, w2[j * 2 + 0], o0);
    o1 = fmaf(acc, w2[j * 2 + 1], o1);
  }
  out[(size_t)node * 2 + 0] = o0;
  out[(size_t)node * 2 + 1] = o1;
}

extern "C" void kernel_launch(void* const* d_in, const int* in_sizes, int n_in,
                              void* d_out, int out_size, void* d_ws, size_t ws_size,
                              hipStream_t stream) {
  const float* x   = (const float*)d_in[0];
  const int*   ei  = (const int*)d_in[1];
  const float* W0  = (const float*)d_in[2];
  const float* as0 = (const float*)d_in[3];
  const float* ad0 = (const float*)d_in[4];
  const float* g0  = (const float*)d_in[6];
  const float* be0 = (const float*)d_in[7];
  const float* W1  = (const float*)d_in[8];
  const float* as1 = (const float*)d_in[9];
  const float* ad1 = (const float*)d_in[10];
  const float* g1  = (const float*)d_in[12];
  const float* be1 = (const float*)d_in[13];
  const float* W2  = (const float*)d_in[14];
  const float* as2 = (const float*)d_in[15];
  const float* ad2 = (const float*)d_in[16];
  const float* g2  = (const float*)d_in[18];
  const float* be2 = (const float*)d_in[19];
  const float* cw1 = (const float*)d_in[20];
  const float* cb1 = (const float*)d_in[21];
  const float* cw2 = (const float*)d_in[22];
  const float* cb2 = (const float*)d_in[23];
  // b0/b1/b2 cancel in the following BatchNorm -> skipped.

  const int n = in_sizes[0] / 128;
  const int E = in_sizes[1] / 2;
  const int n64 = cdiv(n, 64) * 64;

  const int NBLK = cdiv(E, EPB);
  const int NB = cdiv(n, 256);
  const int m = NB * NBLK;

  // ---- workspace layout ----
  unsigned short* Ab  = (unsigned short*)d_ws;            // n64*128
  unsigned short* Bb  = Ab + (size_t)n64 * 128;           // n64*128
  unsigned short* Pb  = Bb + (size_t)n64 * 128;           // n64*128
  unsigned short* Af  = Pb + (size_t)n64 * 128;           // n64*32
  unsigned short* Wt0 = Af + (size_t)n64 * 32;            // 128*128
  unsigned short* Wt1 = Wt0 + 128 * 128;                  // 128*128
  unsigned short* Wt2 = Wt1 + 128 * 128;                  // 32*128
  float* es    = (float*)(Wt2 + 32 * 128);                // n*4
  float* ed    = es + (size_t)n * 4;                      // n*4
  float* sums0 = ed + (size_t)n * 4;                      // 256
  float* sums1 = sums0 + 256;                             // 256
  float* sums2 = sums1 + 256;                             // 64
  int* counts    = (int*)(sums2 + 64);                    // m
  int* offsets   = counts + m;                            // m+1
  int* row_start = offsets + m + 1;                       // n+1
  int* csr_src   = row_start + n + 1;                     // E+n
  unsigned* ebuf = (unsigned*)(csr_src + E + n);          // E

  // ===== CSR build + weight prep =====
  prep_hist<<<NBLK + 145, 256, 0, stream>>>(ei, counts, W0, W1, W2, Wt0, Wt1, Wt2,
                                            sums0, sums1, sums2, E, NBLK, NB);
  csr_scan2<<<1, 1024, 0, stream>>>(counts, offsets, m);
  csr_part<<<NBLK, 256, 0, stream>>>(ei, offsets, ebuf, E, NBLK, NB);
  csr_bucket<<<NB, 256, 0, stream>>>(ebuf, offsets, row_start, csr_src, n, E, NBLK, NB);

  // ===== layer 0 (fp32 x read directly) =====
  gemm_mfma<128, 128, 4, false, true><<<cdiv(n, 64), 256, 0, stream>>>(
      nullptr, x, Wt0, as0, ad0, nullptr, nullptr, nullptr, Pb, es, ed, n);
  node_agg<4, 32><<<cdiv(n, 16), 256, 0, stream>>>(row_start, csr_src, es, ed, Pb, Ab, n);
  bn_stats2<128><<<1024, 256, 0, stream>>>(Ab, sums0, n);

  // ===== layer 1 (BN+ELU fused on load) =====
  gemm_mfma<128, 128, 4, true, false><<<cdiv(n, 64), 256, 0, stream>>>(
      Ab, nullptr, Wt1, as1, ad1, sums0, g0, be0, Pb, es, ed, n);
  node_agg<4, 32><<<cdiv(n, 16), 256, 0, stream>>>(row_start, csr_src, es, ed, Pb, Bb, n);
  bn_stats2<128><<<1024, 256, 0, stream>>>(Bb, sums1, n);

  // ===== layer 2 =====
  gemm_mfma<128, 32, 1, true, false><<<cdiv(n, 64), 256, 0, stream>>>(
      Bb, nullptr, Wt2, as2, ad2, sums1, g1, be1, Pb, es, ed, n);
  node_agg<1, 32><<<cdiv(n, 64), 256, 0, stream>>>(row_start, csr_src, es, ed, Pb, Af, n);
  bn_stats2<32><<<512, 256, 0, stream>>>(Af, sums2, n);

  // ===== head MLP with fused BN+ELU =====
  mlp_head<<<cdiv(n, 256), 256, 0, stream>>>(Af, sums2, g2, be2, cw1, cb1, cw2, cb2,
                                             (float*)d_out, n);
}

// Round 12
// 393.812 us; speedup vs baseline: 1.1727x; 1.0749x over previous
//
#include <hip/hip_runtime.h>

static constexpr float SLOPE = 0.2f;
static constexpr float BN_EPS = 1e-5f;

static inline int cdiv(long long a, long long b) { return (int)((a + b - 1) / b); }

typedef __attribute__((ext_vector_type(8))) short short8;
typedef __attribute__((ext_vector_type(4))) float f32x4;

__device__ __forceinline__ unsigned short f2bf(float f) {
  unsigned u = __float_as_uint(f);
  u += 0x7fff + ((u >> 16) & 1);          // round-to-nearest-even
  return (unsigned short)(u >> 16);
}
__device__ __forceinline__ float bf2f(unsigned short h) {
  return __uint_as_float((unsigned)h << 16);
}

// ====================== CSR build: bucket-partitioned, LDS-staged ======================
static constexpr int EPB = 8192;        // edges per partition block
static constexpr int BCAP = 12288;      // LDS staging capacity in csr_bucket

// ---- merged: per-block bucket histogram + weight transpose + bn-sum zeroing ----
// grid = NBLK + 145
__global__ void prep_hist(const int* __restrict__ ei, int* __restrict__ counts,
                          const float* __restrict__ W0, const float* __restrict__ W1,
                          const float* __restrict__ W2,
                          unsigned short* __restrict__ Wt0, unsigned short* __restrict__ Wt1,
                          unsigned short* __restrict__ Wt2,
                          float* __restrict__ sums0, float* __restrict__ sums1,
                          float* __restrict__ sums2,
                          int E, int NBLK, int NB) {
  const int tid = threadIdx.x;
  const int blk = blockIdx.x;
  if (blk < NBLK) {                      // histogram role
    __shared__ int cnt[256];
    cnt[tid] = 0;
    __syncthreads();
    const int i0 = blk * EPB;
    const int i1 = min(E, i0 + EPB);
    for (int i = i0 + tid; i < i1; i += 256) atomicAdd(&cnt[ei[E + i] >> 8], 1);
    __syncthreads();
    if (tid < NB) counts[tid * NBLK + blk] = cnt[tid];
    return;
  }
  const int b = blk - NBLK;
  if (b < 64) {                          // Wt0[j][k] = W0[k][j], 128x128
    int o = b * 256 + tid;
    int j = o >> 7, k = o & 127;
    Wt0[o] = f2bf(W0[k * 128 + j]);
  } else if (b < 128) {
    int o = (b - 64) * 256 + tid;
    int j = o >> 7, k = o & 127;
    Wt1[o] = f2bf(W1[k * 128 + j]);
  } else if (b < 144) {                  // Wt2[j][k] = W2[k][j], 32x128
    int o = (b - 128) * 256 + tid;
    int j = o >> 7, k = o & 127;
    Wt2[o] = f2bf(W2[k * 32 + j]);
  } else {
    sums0[tid] = 0.f;
    sums1[tid] = 0.f;
    if (tid < 64) sums2[tid] = 0.f;
  }
}

// ---- chunked 2-pass exclusive scan, single block of 1024 ----
__global__ void csr_scan2(const int* __restrict__ counts, int* __restrict__ offsets, int m) {
  __shared__ int wtot[16];
  const int tid = threadIdx.x;
  const int lane = tid & 63, wv = tid >> 6;
  const int CH = (m + 1023) >> 10;
  const int lo = min(m, tid * CH);
  const int hi = min(m, lo + CH);
  int sum = 0;
  for (int i = lo; i < hi; ++i) sum += counts[i];
  int x = sum;
#pragma unroll
  for (int off = 1; off < 64; off <<= 1) {
    int y = __shfl_up(x, off);
    if (lane >= off) x += y;
  }
  if (lane == 63) wtot[wv] = x;
  __syncthreads();
  int add = 0;
  for (int w = 0; w < wv; ++w) add += wtot[w];
  int run = x - sum + add;
  for (int i = lo; i < hi; ++i) { offsets[i] = run; run += counts[i]; }
  if (hi == m) offsets[m] = run;
}

// ---- partition edges into bucket-major packed runs via LDS staging ----
__global__ __launch_bounds__(256) void csr_part(const int* __restrict__ ei,
                                                const int* __restrict__ offsets,
                                                unsigned* __restrict__ ebuf,
                                                int E, int NBLK, int NB) {
  __shared__ unsigned stage[EPB];        // 32 KB
  __shared__ int cnt[256], sstart[256], cur[256], goff[256];
  __shared__ int wtot[4];
  const int tid = threadIdx.x;
  const int blk = blockIdx.x;
  const int lane = tid & 63, wv = tid >> 6;
  cnt[tid] = 0;
  if (tid < NB) goff[tid] = offsets[tid * NBLK + blk];
  __syncthreads();
  const int i0 = blk * EPB;
  const int i1 = min(E, i0 + EPB);
  for (int i = i0 + tid; i < i1; i += 256) atomicAdd(&cnt[ei[E + i] >> 8], 1);
  __syncthreads();
  int v = cnt[tid];
  int x = v;
#pragma unroll
  for (int off = 1; off < 64; off <<= 1) {
    int y = __shfl_up(x, off);
    if (lane >= off) x += y;
  }
  if (lane == 63) wtot[wv] = x;
  __syncthreads();
  int add = 0;
  for (int w = 0; w < wv; ++w) add += wtot[w];
  int excl = x - v + add;
  sstart[tid] = excl;
  cur[tid] = excl;
  __syncthreads();
  for (int i = i0 + tid; i < i1; i += 256) {
    int s = ei[i], d = ei[E + i];
    int p = atomicAdd(&cur[d >> 8], 1);
    stage[p] = ((unsigned)s << 8) | (unsigned)(d & 255);
  }
  __syncthreads();
  for (int b = wv; b < NB; b += 4) {
    const int ls = sstart[b], le = cur[b];
    const int gbase = goff[b];
    for (int e = ls + lane; e < le; e += 64) ebuf[gbase + (e - ls)] = stage[e];
  }
}

// ---- per-bucket CSR segment build via LDS staging, coalesced final write ----
__global__ __launch_bounds__(256) void csr_bucket(const unsigned* __restrict__ ebuf,
                                                  const int* __restrict__ offsets,
                                                  int* __restrict__ row_start,
                                                  int* __restrict__ csr_src,
                                                  int n, int E, int NBLK, int NB) {
  __shared__ unsigned stage[BCAP];       // 48 KB
  __shared__ int deg[256], cur[256];
  __shared__ int wtot[4];
  const int b = blockIdx.x;
  const int base = b << 8;
  const int nn = min(256, n - base);
  const int estart = offsets[b * NBLK];
  const int eend = (b + 1 < NB) ? offsets[(b + 1) * NBLK] : E;
  const int gstart = estart + base;
  const int tid = threadIdx.x;
  const int lane = tid & 63, wv = tid >> 6;
  deg[tid] = (tid < nn) ? 1 : 0;
  __syncthreads();
  for (int j = estart + tid; j < eend; j += 256) atomicAdd(&deg[ebuf[j] & 255u], 1);
  __syncthreads();
  int v = deg[tid];
  int x = v;
#pragma unroll
  for (int off = 1; off < 64; off <<= 1) {
    int y = __shfl_up(x, off);
    if (lane >= off) x += y;
  }
  if (lane == 63) wtot[wv] = x;
  __syncthreads();
  int add = 0;
  for (int w = 0; w < wv; ++w) add += wtot[w];
  int excl = x - v + add;
  cur[tid] = excl;
  if (tid < nn) row_start[base + tid] = gstart + excl;
  if (b == 0 && tid == 0) row_start[n] = E + n;
  __syncthreads();
  if (tid < nn) {
    int p = atomicAdd(&cur[tid], 1);
    if (p < BCAP) stage[p] = (unsigned)(base + tid);
    else csr_src[gstart + p] = base + tid;
  }
  for (int j = estart + tid; j < eend; j += 256) {
    unsigned pk = ebuf[j];
    int p = atomicAdd(&cur[pk & 255u], 1);
    if (p < BCAP) stage[p] = pk >> 8;
    else csr_src[gstart + p] = (int)(pk >> 8);
  }
  __syncthreads();
  const int tot = min(eend - estart + nn, BCAP);
  for (int e = tid; e < tot; e += 256) csr_src[gstart + e] = (int)stage[e];
}

// ====== MFMA projection GEMM + fused attn scores; LDS-staged coalesced P stores ======
template<int IC, int OC, int H, bool BN, bool AF32>
__global__ void gemm_mfma(const unsigned short* __restrict__ Act,
                          const float* __restrict__ Axf,
                          const unsigned short* __restrict__ Wt,
                          const float* __restrict__ a_s, const float* __restrict__ a_d,
                          const float* __restrict__ bnsums, const float* __restrict__ g,
                          const float* __restrict__ be,
                          unsigned short* __restrict__ Pb, float* __restrict__ es,
                          float* __restrict__ ed, int n) {
  constexpr int NF = OC / 16;                  // column fragments
  __shared__ float s_sc[IC], s_sf[IC];
  __shared__ unsigned short s_stage[4 * 16 * OC];
  const int tid = threadIdx.x;                 // 256 = 4 waves; wave covers 16 rows
  if (BN) {
    const float inv_n = 1.f / (float)n;
    for (int c = tid; c < IC; c += 256) {
      float mu = bnsums[c] * inv_n;
      float var = bnsums[IC + c] * inv_n - mu * mu;
      float s = g[c] * rsqrtf(var + BN_EPS);
      s_sc[c] = s;
      s_sf[c] = be[c] - mu * s;
    }
    __syncthreads();
  }
  const int lane = tid & 63;
  const int l15 = lane & 15;
  const int lk = lane >> 4;                    // 0..3
  const int wid = tid >> 6;
  const int node0 = blockIdx.x * 64 + wid * 16;
  const int arow = node0 + l15;
  const int ar = AF32 ? min(arow, n - 1) : arow;

  f32x4 acc[NF];
#pragma unroll
  for (int cb = 0; cb < NF; ++cb) acc[cb] = (f32x4){0.f, 0.f, 0.f, 0.f};

#pragma unroll
  for (int kc = 0; kc < IC / 32; ++kc) {
    const int kbase = kc * 32 + lk * 8;
    short8 a;
    if (AF32) {
      float4 u0 = *(const float4*)(Axf + (size_t)ar * IC + kbase);
      float4 u1 = *(const float4*)(Axf + (size_t)ar * IC + kbase + 4);
      a[0] = (short)f2bf(u0.x); a[1] = (short)f2bf(u0.y);
      a[2] = (short)f2bf(u0.z); a[3] = (short)f2bf(u0.w);
      a[4] = (short)f2bf(u1.x); a[5] = (short)f2bf(u1.y);
      a[6] = (short)f2bf(u1.z); a[7] = (short)f2bf(u1.w);
    } else {
      a = *(const short8*)(Act + (size_t)ar * IC + kbase);
    }
    if (BN) {
      short8 ta;
#pragma unroll
      for (int i = 0; i < 8; ++i) {
        float v = bf2f((unsigned short)a[i]);
        float y = fmaf(v, s_sc[kbase + i], s_sf[kbase + i]);
        y = (y > 0.f) ? y : (__expf(y) - 1.f);
        ta[i] = (short)f2bf(y);
      }
      a = ta;
    }
#pragma unroll
    for (int cb = 0; cb < NF; ++cb) {
      short8 b = *(const short8*)(Wt + (size_t)(cb * 16 + l15) * IC + kbase);
      acc[cb] = __builtin_amdgcn_mfma_f32_16x16x32_bf16(a, b, acc[cb], 0, 0, 0);
    }
  }

  // epilogue: fused es/ed scores + stage P into per-wave LDS tile
  unsigned short* st = s_stage + wid * 16 * OC;
  float esum[4] = {0.f, 0.f, 0.f, 0.f}, edum[4] = {0.f, 0.f, 0.f, 0.f};
#pragma unroll
  for (int cb = 0; cb < NF; ++cb) {
    const int j = cb * 16 + l15;
    const float asv = a_s[j];
    const float adv = a_d[j];
#pragma unroll
    for (int i = 0; i < 4; ++i) {
      float p = acc[cb][i];
      st[(lk * 4 + i) * OC + j] = f2bf(p);
      float ps = p * asv, pd = p * adv;
#pragma unroll
      for (int mm = 1; mm <= 8; mm <<= 1) {
        ps += __shfl_xor(ps, mm);
        pd += __shfl_xor(pd, mm);
      }
      esum[i] += ps;
      edum[i] += pd;
    }
    if (cb & 1) {
      const int h = cb >> 1;
#pragma unroll
      for (int i = 0; i < 4; ++i) {
        int node = node0 + lk * 4 + i;
        if (l15 == 0 && node < n) {
          es[node * H + h] = esum[i];
          ed[node * H + h] = edum[i];
        }
        esum[i] = 0.f;
        edum[i] = 0.f;
      }
    }
  }
  // coalesced P store (wave-synchronous LDS reuse; same wave wrote st)
  for (int idx = lane; idx < 2 * OC; idx += 64) {     // 16 rows * OC/8 uint4
    int r = idx / (OC / 8);
    int q = idx % (OC / 8);
    int node = node0 + r;
    if (node < n)
      *(uint4*)(Pb + (size_t)node * OC + q * 8) = *(const uint4*)(st + r * OC + q * 8);
  }
}

// ======== fused max-free softmax + weighted gather (unroll-4, 4-ahead prefetch) ========
// Barrier-free by design (BN-stat fusion regressed twice: R6/R10).
template<int H, int C>
__global__ void node_agg(const int* __restrict__ row_start, const int* __restrict__ csr_src,
                         const float* __restrict__ es, const float* __restrict__ ed,
                         const unsigned short* __restrict__ Pb, unsigned short* __restrict__ Ob,
                         int n) {
  constexpr int HC = H * C;
  constexpr int TPN = HC / 8;                  // threads per node (8 bf16 = 16 B each)
  const int tid = threadIdx.x;                 // blockDim = 256
  const int t = tid % TPN;
  const int node = blockIdx.x * (256 / TPN) + tid / TPN;
  if (node >= n) return;
  const int h = (t * 8) / C;
  const int e0 = row_start[node];
  const int e1 = row_start[node + 1];
  const float edd = ed[node * H + h];
  const uint4* P4 = (const uint4*)Pb;
  float a0 = 0.f, a1 = 0.f, a2 = 0.f, a3 = 0.f;
  float a4 = 0.f, a5 = 0.f, a6 = 0.f, a7 = 0.f;
  float den = 0.f;
  int s0 = csr_src[e0];                        // deg >= 1 (self loop)
  int s1 = (e0 + 1 < e1) ? csr_src[e0 + 1] : s0;
  int s2 = (e0 + 2 < e1) ? csr_src[e0 + 2] : s0;
  int s3 = (e0 + 3 < e1) ? csr_src[e0 + 3] : s0;
  for (int j = e0; j < e1; j += 4) {
    const int nj = j + 4;
    int t0 = (nj     < e1) ? csr_src[nj]     : s0;
    int t1 = (nj + 1 < e1) ? csr_src[nj + 1] : s0;
    int t2 = (nj + 2 < e1) ? csr_src[nj + 2] : s0;
    int t3 = (nj + 3 < e1) ? csr_src[nj + 3] : s0;
    float x0 = es[s0 * H + h], x1 = es[s1 * H + h];
    float x2 = es[s2 * H + h], x3 = es[s3 * H + h];
    uint4 p0 = P4[(size_t)s0 * TPN + t];
    uint4 p1 = P4[(size_t)s1 * TPN + t];
    uint4 p2 = P4[(size_t)s2 * TPN + t];
    uint4 p3 = P4[(size_t)s3 * TPN + t];
    x0 += edd; x0 = fmaxf(x0, SLOPE * x0);
    x1 += edd; x1 = fmaxf(x1, SLOPE * x1);
    x2 += edd; x2 = fmaxf(x2, SLOPE * x2);
    x3 += edd; x3 = fmaxf(x3, SLOPE * x3);
    float w0 = __expf(x0);
    float w1 = (j + 1 < e1) ? __expf(x1) : 0.f;
    float w2 = (j + 2 < e1) ? __expf(x2) : 0.f;
    float w3 = (j + 3 < e1) ? __expf(x3) : 0.f;
    den += (w0 + w1) + (w2 + w3);
    a0 = fmaf(w0, __uint_as_float(p0.x << 16), a0);
    a1 = fmaf(w0, __uint_as_float(p0.x & 0xffff0000u), a1);
    a2 = fmaf(w0, __uint_as_float(p0.y << 16), a2);
    a3 = fmaf(w0, __uint_as_float(p0.y & 0xffff0000u), a3);
    a4 = fmaf(w0, __uint_as_float(p0.z << 16), a4);
    a5 = fmaf(w0, __uint_as_float(p0.z & 0xffff0000u), a5);
    a6 = fmaf(w0, __uint_as_float(p0.w << 16), a6);
    a7 = fmaf(w0, __uint_as_float(p0.w & 0xffff0000u), a7);
    a0 = fmaf(w1, __uint_as_float(p1.x << 16), a0);
    a1 = fmaf(w1, __uint_as_float(p1.x & 0xffff0000u), a1);
    a2 = fmaf(w1, __uint_as_float(p1.y << 16), a2);
    a3 = fmaf(w1, __uint_as_float(p1.y & 0xffff0000u), a3);
    a4 = fmaf(w1, __uint_as_float(p1.z << 16), a4);
    a5 = fmaf(w1, __uint_as_float(p1.z & 0xffff0000u), a5);
    a6 = fmaf(w1, __uint_as_float(p1.w << 16), a6);
    a7 = fmaf(w1, __uint_as_float(p1.w & 0xffff0000u), a7);
    a0 = fmaf(w2, __uint_as_float(p2.x << 16), a0);
    a1 = fmaf(w2, __uint_as_float(p2.x & 0xffff0000u), a1);
    a2 = fmaf(w2, __uint_as_float(p2.y << 16), a2);
    a3 = fmaf(w2, __uint_as_float(p2.y & 0xffff0000u), a3);
    a4 = fmaf(w2, __uint_as_float(p2.z << 16), a4);
    a5 = fmaf(w2, __uint_as_float(p2.z & 0xffff0000u), a5);
    a6 = fmaf(w2, __uint_as_float(p2.w << 16), a6);
    a7 = fmaf(w2, __uint_as_float(p2.w & 0xffff0000u), a7);
    a0 = fmaf(w3, __uint_as_float(p3.x << 16), a0);
    a1 = fmaf(w3, __uint_as_float(p3.x & 0xffff0000u), a1);
    a2 = fmaf(w3, __uint_as_float(p3.y << 16), a2);
    a3 = fmaf(w3, __uint_as_float(p3.y & 0xffff0000u), a3);
    a4 = fmaf(w3, __uint_as_float(p3.z << 16), a4);
    a5 = fmaf(w3, __uint_as_float(p3.z & 0xffff0000u), a5);
    a6 = fmaf(w3, __uint_as_float(p3.w << 16), a6);
    a7 = fmaf(w3, __uint_as_float(p3.w & 0xffff0000u), a7);
    s0 = t0; s1 = t1; s2 = t2; s3 = t3;
  }
  float inv = 1.f / (den + 1e-16f);
  uint4 o;
  o.x = (unsigned)f2bf(a0 * inv) | ((unsigned)f2bf(a1 * inv) << 16);
  o.y = (unsigned)f2bf(a2 * inv) | ((unsigned)f2bf(a3 * inv) << 16);
  o.z = (unsigned)f2bf(a4 * inv) | ((unsigned)f2bf(a5 * inv) << 16);
  o.w = (unsigned)f2bf(a6 * inv) | ((unsigned)f2bf(a7 * inv) << 16);
  *(uint4*)(Ob + (size_t)node * HC + t * 8) = o;
}

// ============ BN stats v3: 64 blocks x 1024 threads — short atomic chains ============
// (v2's flush did 1024 serialized global atomics per channel address; that hidden
//  serialization was ~40-50 us per instance. 64 blocks -> 64-deep chains.)
template<int C>
__global__ __launch_bounds__(1024) void bn_stats3(const unsigned short* __restrict__ X,
                                                  float* __restrict__ sums, int n) {
  constexpr int TPR = C / 4;                   // threads per row (4 bf16 each)
  constexpr int RPB = 1024 / TPR;              // rows per block-iteration
  __shared__ float ls[2 * C];
  const int tid = threadIdx.x;
  if (tid < 2 * C) ls[tid] = 0.f;
  __syncthreads();
  const int c4 = (tid % TPR) * 4;
  const int rb = tid / TPR;
  float s0 = 0.f, s1 = 0.f, s2 = 0.f, s3 = 0.f;
  float q0 = 0.f, q1 = 0.f, q2 = 0.f, q3 = 0.f;
  for (int r = blockIdx.x * RPB + rb; r < n; r += gridDim.x * RPB) {
    uint2 v = *(const uint2*)(X + (size_t)r * C + c4);
    float f0 = __uint_as_float(v.x << 16);
    float f1 = __uint_as_float(v.x & 0xffff0000u);
    float f2 = __uint_as_float(v.y << 16);
    float f3 = __uint_as_float(v.y & 0xffff0000u);
    s0 += f0; q0 = fmaf(f0, f0, q0);
    s1 += f1; q1 = fmaf(f1, f1, q1);
    s2 += f2; q2 = fmaf(f2, f2, q2);
    s3 += f3; q3 = fmaf(f3, f3, q3);
  }
  atomicAdd(&ls[c4 + 0], s0);
  atomicAdd(&ls[c4 + 1], s1);
  atomicAdd(&ls[c4 + 2], s2);
  atomicAdd(&ls[c4 + 3], s3);
  atomicAdd(&ls[C + c4 + 0], q0);
  atomicAdd(&ls[C + c4 + 1], q1);
  atomicAdd(&ls[C + c4 + 2], q2);
  atomicAdd(&ls[C + c4 + 3], q3);
  __syncthreads();
  if (tid < 2 * C) unsafeAtomicAdd(&sums[tid], ls[tid]);
}

// ================= final MLP with fused BN+ELU on bf16 load =================
__global__ void mlp_head(const unsigned short* __restrict__ Hf, const float* __restrict__ bnsums,
                         const float* __restrict__ g, const float* __restrict__ be,
                         const float* __restrict__ cw1, const float* __restrict__ cb1,
                         const float* __restrict__ cw2, const float* __restrict__ cb2,
                         float* __restrict__ out, int n) {
  __shared__ float w1[32 * 16];
  __shared__ float b1[16];
  __shared__ float w2[16 * 2];
  __shared__ float b2[2];
  __shared__ float sc[32], sf[32];
  int tid = threadIdx.x;
  for (int i = tid; i < 32 * 16; i += blockDim.x) w1[i] = cw1[i];
  if (tid < 16) b1[tid] = cb1[tid];
  if (tid < 32) w2[tid] = cw2[tid];
  if (tid < 2) b2[tid] = cb2[tid];
  if (tid < 32) {
    float inv_n = 1.f / (float)n;
    float mu = bnsums[tid] * inv_n;
    float var = bnsums[32 + tid] * inv_n - mu * mu;
    float s = g[tid] * rsqrtf(var + BN_EPS);
    sc[tid] = s;
    sf[tid] = be[tid] - mu * s;
  }
  __syncthreads();
  int node = blockIdx.x * blockDim.x + tid;
  if (node >= n) return;
  float x[32];
  const uint4* xp = (const uint4*)(Hf + (size_t)node * 32);
#pragma unroll
  for (int q = 0; q < 4; ++q) {
    uint4 v = xp[q];
    unsigned pr[4] = {v.x, v.y, v.z, v.w};
#pragma unroll
    for (int u = 0; u < 4; ++u) {
      int c = q * 8 + u * 2;
      float va = __uint_as_float(pr[u] << 16);
      float vb = __uint_as_float(pr[u] & 0xffff0000u);
      float ya = fmaf(va, sc[c], sf[c]);
      float yb = fmaf(vb, sc[c + 1], sf[c + 1]);
      x[c] = (ya > 0.f) ? ya : (__expf(ya) - 1.f);
      x[c + 1] = (yb > 0.f) ? yb : (__expf(yb) - 1.f);
    }
  }
  float o0 = b2[0], o1 = b2[1];
#pragma unroll
  for (int j = 0; j < 16; ++j) {
    float acc = b1[j];
#pragma unroll
    for (int k = 0; k < 32; ++k) acc = fmaf(x[k], w1[k * 16 + j], acc);
    acc = (acc > 0.f) ? acc : (__expf(acc) - 1.f);
    o0 = fmaf(acc, w2[j * 2 + 0], o0);
    o1 = fmaf(acc, w2[j * 2 + 1], o1);
  }
  out[(size_t)node * 2 + 0] = o0;
  out[(size_t)node * 2 + 1] = o1;
}

extern "C" void kernel_launch(void* const* d_in, const int* in_sizes, int n_in,
                              void* d_out, int out_size, void* d_ws, size_t ws_size,
                              hipStream_t stream) {
  const float* x   = (const float*)d_in[0];
  const int*   ei  = (const int*)d_in[1];
  const float* W0  = (const float*)d_in[2];
  const float* as0 = (const float*)d_in[3];
  const float* ad0 = (const float*)d_in[4];
  const float* g0  = (const float*)d_in[6];
  const float* be0 = (const float*)d_in[7];
  const float* W1  = (const float*)d_in[8];
  const float* as1 = (const float*)d_in[9];
  const float* ad1 = (const float*)d_in[10];
  const float* g1  = (const float*)d_in[12];
  const float* be1 = (const float*)d_in[13];
  const float* W2  = (const float*)d_in[14];
  const float* as2 = (const float*)d_in[15];
  const float* ad2 = (const float*)d_in[16];
  const float* g2  = (const float*)d_in[18];
  const float* be2 = (const float*)d_in[19];
  const float* cw1 = (const float*)d_in[20];
  const float* cb1 = (const float*)d_in[21];
  const float* cw2 = (const float*)d_in[22];
  const float* cb2 = (const float*)d_in[23];
  // b0/b1/b2 cancel in the following BatchNorm -> skipped.

  const int n = in_sizes[0] / 128;
  const int E = in_sizes[1] / 2;
  const int n64 = cdiv(n, 64) * 64;

  const int NBLK = cdiv(E, EPB);
  const int NB = cdiv(n, 256);
  const int m = NB * NBLK;

  // ---- workspace layout ----
  unsigned short* Ab  = (unsigned short*)d_ws;            // n64*128
  unsigned short* Bb  = Ab + (size_t)n64 * 128;           // n64*128
  unsigned short* Pb  = Bb + (size_t)n64 * 128;           // n64*128
  unsigned short* Af  = Pb + (size_t)n64 * 128;           // n64*32
  unsigned short* Wt0 = Af + (size_t)n64 * 32;            // 128*128
  unsigned short* Wt1 = Wt0 + 128 * 128;                  // 128*128
  unsigned short* Wt2 = Wt1 + 128 * 128;                  // 32*128
  float* es    = (float*)(Wt2 + 32 * 128);                // n*4
  float* ed    = es + (size_t)n * 4;                      // n*4
  float* sums0 = ed + (size_t)n * 4;                      // 256
  float* sums1 = sums0 + 256;                             // 256
  float* sums2 = sums1 + 256;                             // 64
  int* counts    = (int*)(sums2 + 64);                    // m
  int* offsets   = counts + m;                            // m+1
  int* row_start = offsets + m + 1;                       // n+1
  int* csr_src   = row_start + n + 1;                     // E+n
  unsigned* ebuf = (unsigned*)(csr_src + E + n);          // E

  // ===== CSR build + weight prep =====
  prep_hist<<<NBLK + 145, 256, 0, stream>>>(ei, counts, W0, W1, W2, Wt0, Wt1, Wt2,
                                            sums0, sums1, sums2, E, NBLK, NB);
  csr_scan2<<<1, 1024, 0, stream>>>(counts, offsets, m);
  csr_part<<<NBLK, 256, 0, stream>>>(ei, offsets, ebuf, E, NBLK, NB);
  csr_bucket<<<NB, 256, 0, stream>>>(ebuf, offsets, row_start, csr_src, n, E, NBLK, NB);

  // ===== layer 0 (fp32 x read directly) =====
  gemm_mfma<128, 128, 4, false, true><<<cdiv(n, 64), 256, 0, stream>>>(
      nullptr, x, Wt0, as0, ad0, nullptr, nullptr, nullptr, Pb, es, ed, n);
  node_agg<4, 32><<<cdiv(n, 16), 256, 0, stream>>>(row_start, csr_src, es, ed, Pb, Ab, n);
  bn_stats3<128><<<64, 1024, 0, stream>>>(Ab, sums0, n);

  // ===== layer 1 (BN+ELU fused on load) =====
  gemm_mfma<128, 128, 4, true, false><<<cdiv(n, 64), 256, 0, stream>>>(
      Ab, nullptr, Wt1, as1, ad1, sums0, g0, be0, Pb, es, ed, n);
  node_agg<4, 32><<<cdiv(n, 16), 256, 0, stream>>>(row_start, csr_src, es, ed, Pb, Bb, n);
  bn_stats3<128><<<64, 1024, 0, stream>>>(Bb, sums1, n);

  // ===== layer 2 =====
  gemm_mfma<128, 32, 1, true, false><<<cdiv(n, 64), 256, 0, stream>>>(
      Bb, nullptr, Wt2, as2, ad2, sums1, g1, be1, Pb, es, ed, n);
  node_agg<1, 32><<<cdiv(n, 64), 256, 0, stream>>>(row_start, csr_src, es, ed, Pb, Af, n);
  bn_stats3<32><<<64, 1024, 0, stream>>>(Af, sums2, n);

  // ===== head MLP with fused BN+ELU =====
  mlp_head<<<cdiv(n, 256), 256, 0, stream>>>(Af, sums2, g2, be2, cw1, cb1, cw2, cb2,
                                             (float*)d_out, n);
}